// Round 4
// baseline (924.791 us; speedup 1.0000x reference)
//
#include <hip/hip_runtime.h>
#include <hip/hip_bf16.h>

#define Nn 20000
#define Npad 20160
#define Dd 256
#define Ff 256
#define Kc 32

typedef __attribute__((ext_vector_type(8))) short short8;
typedef __attribute__((ext_vector_type(4))) short short4_t;
typedef __attribute__((ext_vector_type(4))) float float4_t;
typedef __attribute__((ext_vector_type(2))) unsigned int uint2_t;

static __device__ __forceinline__ short f2bf(float x) {
    union { float f; unsigned u; } v; v.f = x;
    unsigned r = v.u + 0x7FFFu + ((v.u >> 16) & 1u);   // round-to-nearest-even
    return (short)(r >> 16);
}
static __device__ __forceinline__ short4_t cvt4(float4_t v) {
    short4_t r; r[0] = f2bf(v[0]); r[1] = f2bf(v[1]); r[2] = f2bf(v[2]); r[3] = f2bf(v[3]);
    return r;
}
static __device__ __forceinline__ unsigned cvtpk(float a, float b) {
    unsigned r;
    asm("v_cvt_pk_bf16_f32 %0, %1, %2" : "=v"(r) : "v"(a), "v"(b));
    return r;   // lo = bf16(a), hi = bf16(b)  (RNE)
}

// ---------------- K1: node = h @ W1  [N,32] fp32 ----------------
__global__ __launch_bounds__(256) void k_node(const float* __restrict__ h,
                                              const float* __restrict__ W1,
                                              float* __restrict__ node) {
    int t = blockIdx.x * 256 + threadIdx.x;     // N*32 threads
    int n = t >> 5, k = t & 31;
    if (n >= Nn) return;
    const float4_t* hr = (const float4_t*)(h + (size_t)n * Dd);
    float s = 0.f;
    #pragma unroll 8
    for (int d4 = 0; d4 < 64; ++d4) {
        float4_t hv = hr[d4];
        #pragma unroll
        for (int j = 0; j < 4; ++j) s += hv[j] * W1[(d4 * 4 + j) * Kc + k];
    }
    node[n * Kc + k] = s;
}

// ------- K2: pack W2 (fp32 [32][256][256]) -> bf16 B-fragment order -------
__global__ __launch_bounds__(256) void k_packW2(const float* __restrict__ W2,
                                                short* __restrict__ P) {
    int t = blockIdx.x * 256 + threadIdx.x;     // 262144 threads
    int lane = t & 63;
    int cf = (t >> 6) & 15;
    int dc = (t >> 10) & 7;
    int kk = t >> 13;
    int col = cf * 16 + (lane & 15);
    int d0  = dc * 32 + (lane >> 4) * 8;
    const float* src = W2 + ((size_t)(kk * Dd + d0)) * Ff + col;
    short8 v;
    #pragma unroll
    for (int j = 0; j < 8; ++j) v[j] = f2bf(src[(size_t)j * Ff]);
    *(short8*)(P + (size_t)t * 8) = v;
}

// ---------------- K3: x_pre, stored transposed bf16 [256][Npad] ----------------
// Pad columns [Nn, Npad) are zeroed every launch (k_aggr's tail reads them).
__global__ __launch_bounds__(256, 2) void k_xpre(const float* __restrict__ h,
                                                 const float* __restrict__ node,
                                                 const short* __restrict__ P,
                                                 short* __restrict__ xpre_t) {
    __shared__ short hlds[64 * 264];        // bf16 h tile, padded stride 264
    __shared__ float ntl[32 * 64];          // node transposed [kk][n_local]
    int t = threadIdx.x;
    int n0 = blockIdx.x * 64;

    #pragma unroll
    for (int i = 0; i < 16; ++i) {
        int c = t + i * 256;                // 4096 float4 chunks
        int row = c >> 6, cc = c & 63;
        int n = n0 + row; if (n > Nn - 1) n = Nn - 1;
        float4_t v = *(const float4_t*)(h + (size_t)n * Dd + cc * 4);
        *(short4_t*)&hlds[row * 264 + cc * 4] = cvt4(v);
    }
    #pragma unroll
    for (int i = 0; i < 8; ++i) {
        int idx = t + i * 256;              // 2048
        int nl = idx >> 5, k = idx & 31;
        int n = n0 + nl; if (n > Nn - 1) n = Nn - 1;
        ntl[k * 64 + nl] = node[(size_t)n * Kc + k];
    }
    __syncthreads();

    int lane = t & 63, w = t >> 6;
    int arow = lane & 15;
    int asel = (lane >> 4) * 8;
    float4_t acc[4][4];
    #pragma unroll
    for (int a = 0; a < 4; ++a)
        #pragma unroll
        for (int b2 = 0; b2 < 4; ++b2) acc[a][b2] = (float4_t){0.f, 0.f, 0.f, 0.f};

    for (int kk = 0; kk < 32; ++kk) {
        float4_t T[4][4];
        #pragma unroll
        for (int a = 0; a < 4; ++a)
            #pragma unroll
            for (int b2 = 0; b2 < 4; ++b2) T[a][b2] = (float4_t){0.f, 0.f, 0.f, 0.f};
        #pragma unroll
        for (int dc = 0; dc < 8; ++dc) {
            short8 af[4], bfr[4];
            #pragma unroll
            for (int rf = 0; rf < 4; ++rf)
                af[rf] = *(const short8*)&hlds[(rf * 16 + arow) * 264 + dc * 32 + asel];
            #pragma unroll
            for (int cf = 0; cf < 4; ++cf)
                bfr[cf] = *(const short8*)(P + ((size_t)(((kk * 8 + dc) * 16 + w * 4 + cf) * 64 + lane)) * 8);
            #pragma unroll
            for (int rf = 0; rf < 4; ++rf)
                #pragma unroll
                for (int cf = 0; cf < 4; ++cf)
                    T[rf][cf] = __builtin_amdgcn_mfma_f32_16x16x32_bf16(af[rf], bfr[cf], T[rf][cf], 0, 0, 0);
        }
        #pragma unroll
        for (int rf = 0; rf < 4; ++rf) {
            float4_t sc = *(const float4_t*)&ntl[kk * 64 + rf * 16 + (lane >> 4) * 4];
            #pragma unroll
            for (int cf = 0; cf < 4; ++cf)
                #pragma unroll
                for (int r = 0; r < 4; ++r)
                    acc[rf][cf][r] += sc[r] * T[rf][cf][r];
        }
    }

    #pragma unroll
    for (int rf = 0; rf < 4; ++rf) {
        int nl = rf * 16 + (lane >> 4) * 4;
        #pragma unroll
        for (int cf = 0; cf < 4; ++cf) {
            int f = w * 64 + cf * 16 + (lane & 15);
            #pragma unroll
            for (int r = 0; r < 4; ++r) {
                int n = n0 + nl + r;
                if (n < Nn)       xpre_t[(size_t)f * Npad + n] = f2bf(acc[rf][cf][r]);
                else if (n < Npad) xpre_t[(size_t)f * Npad + n] = 0;
            }
        }
    }
}

// ---------------- K4: out = relu(adj @ x_pre + node @ b) ----------------
// BM=80 (250 blocks), BN=256, BK=320 (63 steps, 1280B/row DRAM bursts),
// 512 threads. Single-A reg staging (WRITEA's counted vmcnt wait IS the BW
// pacing), B loaded per step from L2/L3, raw s_barrier (lgkmcnt only).
#define BM 80
#define BK 320
#define DCN 10              // BK/32
#define ASTR 328            // alds row stride in shorts (656B; 2-way banks = free)
#define NSTEP 63            // 63*320 = 20160 = Npad
#define ALIM (Nn * Nn - 4)  // clamp: last block's tail reads stay in-bounds

__global__ __launch_bounds__(512, 2) void k_aggr(const float* __restrict__ adj,
                                                 const short* __restrict__ xpre_t,
                                                 const float* __restrict__ node,
                                                 const float* __restrict__ bb,
                                                 float* __restrict__ out) {
    __shared__ short alds[2][BM * ASTR];    // 2 x 52.5 KB
    __shared__ float nlds[BM * 32];         // 10.24 KB
    __shared__ float blds[32 * 256];        // 32.77 KB

    const int t = threadIdx.x;
    const int m0 = blockIdx.x * BM;
    const int lane = t & 63, w = t >> 6;
    const int kb = (lane >> 4) * 8;

    // stage node tile + b for the epilogue
    #pragma unroll
    for (int i = 0; i < 5; ++i) { int idx = t + i * 512; nlds[idx] = node[(size_t)m0 * 32 + idx]; }
    #pragma unroll
    for (int i = 0; i < 4; ++i) { int idx = t + i * 512; *(float4_t*)&blds[idx * 4] = *(const float4_t*)(bb + (size_t)idx * 4); }

    // adj staging geometry: 80*320 floats = 6400 float4 chunks; 12-13/thread
    const bool v13 = (t < 256);
    int gbase[13], loff[13];
    #pragma unroll
    for (int i = 0; i < 13; ++i) {
        int c = t + i * 512; if (c >= 6400) c = 0;
        int row = c / 80, col = c % 80;     // 80 float4 per row-chunk
        gbase[i] = (m0 + row) * Nn + col * 4;   // fits int (max ~4.0e8)
        loff[i]  = row * ASTR + col * 4;
    }
    const short* xrow0 = xpre_t + (long)(w * 32 + (lane & 15)) * Npad + kb;
    const short* xrow1 = xrow0 + 16L * Npad;

    float4_t acc[5][2];
    #pragma unroll
    for (int rf = 0; rf < 5; ++rf)
        #pragma unroll
        for (int cf = 0; cf < 2; ++cf) acc[rf][cf] = (float4_t){0.f, 0.f, 0.f, 0.f};

    float4_t A[13];
    short8 b0[DCN], b1[DCN];

#define LOADA(s_) do { _Pragma("unroll") for (int i = 0; i < 13; ++i) \
        if (i < 12 || v13) { int idx = gbase[i] + (s_) * BK; \
            if (idx > ALIM) idx = ALIM; \
            A[i] = *(const float4_t*)(adj + idx); } } while (0)

#define WRITEA(buf_) do { _Pragma("unroll") for (int i = 0; i < 13; ++i) \
        if (i < 12 || v13) { \
            uint2_t u = { cvtpk(A[i][0], A[i][1]), cvtpk(A[i][2], A[i][3]) }; \
            *(uint2_t*)&alds[buf_][loff[i]] = u; } } while (0)

#define SYNC() do { asm volatile("s_waitcnt lgkmcnt(0)" ::: "memory"); \
                    __builtin_amdgcn_s_barrier(); } while (0)

    // prologue: stage step 0 into alds[0]
    LOADA(0);
    WRITEA(0);
    SYNC();

    #pragma unroll 1
    for (int s = 0; s < NSTEP; ++s) {
        // B fragments for this step (L2/L3-resident xpre)
        const short* xr0 = xrow0 + (long)s * BK;
        const short* xr1 = xrow1 + (long)s * BK;
        #pragma unroll
        for (int dc = 0; dc < DCN; ++dc) {
            b0[dc] = *(const short8*)(xr0 + dc * 32);
            b1[dc] = *(const short8*)(xr1 + dc * 32);
        }
        // issue next adj tile (HBM) — consumed by WRITEA at step end
        if (s + 1 < NSTEP) LOADA(s + 1);

        const short* ar = alds[s & 1];
        #pragma unroll
        for (int dc = 0; dc < DCN; ++dc) {
            #pragma unroll
            for (int rf = 0; rf < 5; ++rf) {
                short8 afr = *(const short8*)&ar[(rf * 16 + (lane & 15)) * ASTR + dc * 32 + kb];
                acc[rf][0] = __builtin_amdgcn_mfma_f32_16x16x32_bf16(afr, b0[dc], acc[rf][0], 0, 0, 0);
                acc[rf][1] = __builtin_amdgcn_mfma_f32_16x16x32_bf16(afr, b1[dc], acc[rf][1], 0, 0, 0);
            }
        }
        if (s + 1 < NSTEP) WRITEA((s & 1) ^ 1);
        SYNC();
    }

    // epilogue: + node@b, relu, store fp32
    #pragma unroll
    for (int rf = 0; rf < 5; ++rf) {
        #pragma unroll
        for (int cf = 0; cf < 2; ++cf) {
            int fl = w * 32 + cf * 16 + (lane & 15);
            #pragma unroll
            for (int r = 0; r < 4; ++r) {
                int nl = rf * 16 + (lane >> 4) * 4 + r;
                float bias = 0.f;
                #pragma unroll 8
                for (int k = 0; k < 32; ++k) bias += nlds[nl * 32 + k] * blds[k * 256 + fl];
                float v = acc[rf][cf][r] + bias;
                out[(size_t)(m0 + nl) * 256 + fl] = v > 0.f ? v : 0.f;
            }
        }
    }
#undef LOADA
#undef WRITEA
#undef SYNC
}

extern "C" void kernel_launch(void* const* d_in, const int* in_sizes, int n_in,
                              void* d_out, int out_size, void* d_ws, size_t ws_size,
                              hipStream_t stream) {
    const float* h   = (const float*)d_in[0];
    const float* adj = (const float*)d_in[1];
    const float* W1  = (const float*)d_in[2];
    const float* W2  = (const float*)d_in[3];
    const float* b   = (const float*)d_in[4];
    float* out = (float*)d_out;

    char* ws = (char*)d_ws;
    float* node   = (float*)ws;                               // 2,560,000 B
    short* P      = (short*)(ws + 2560000);                   // 4,194,304 B
    short* xpre_t = (short*)(ws + 2560000 + 4194304);         // 10,321,920 B (256 x 20160)

    k_node  <<<2500, 256, 0, stream>>>(h, W1, node);
    k_packW2<<<1024, 256, 0, stream>>>(W2, P);
    k_xpre  <<<315,  256, 0, stream>>>(h, node, P, xpre_t);
    k_aggr  <<<250,  512, 0, stream>>>(adj, xpre_t, node, b, out);
}